// Round 11
// baseline (134.742 us; speedup 1.0000x reference)
//
#include <hip/hip_runtime.h>

#define NBATCH 4
#define DDIM   256
#define NN     4096
#define MM     4096
#define NCHUNK 8          // m-chunks (split-K across workgroups)
#define MCHUNK 512        // m per chunk
#define LOG2E  1.44269504088896340736f

using half8   = __attribute__((ext_vector_type(8))) _Float16;
using floatx4 = __attribute__((ext_vector_type(4))) float;

// Fragment-ordered fp16 layout (per batch): half8 at ((blk*8 + ds)*4 + quad)*16 + l15
// covers point p = blk*16 + l15, dims d = ds*32 + quad*8 .. +7.  A-frag reads are
// lane-contiguous 1 KB global loads -> perfectly coalesced, L2-resident per XCD.

// ---------- prep: emb[b][d][n] fp32 -> fragment-ordered fp16; fused Vt{v,yy} ----------
__global__ __launch_bounds__(256) void k_prep(const float* __restrict__ src_emb,
                                              const float* __restrict__ tgt_emb,
                                              const float* __restrict__ tgt,
                                              _Float16* __restrict__ Qf,
                                              _Float16* __restrict__ Kf,
                                              float4* __restrict__ Vt) {
    __shared__ float psum[4][64];
    int i = blockIdx.x;                            // 512 = xcd(8) x j(64)
    int xcd = i & 7, j = i >> 3;
    int b = xcd >> 1, nhalf = xcd & 1;             // matches flash's XCD mapping
    int tensor = j & 1, sub = j >> 1;              // sub 0..31
    int n0 = nhalf * 2048 + sub * 64;
    const float* in = tensor ? tgt_emb : src_emb;
    _Float16* outp  = tensor ? Kf : Qf;
    const float scale = tensor ? 1.0f : 2.0f * LOG2E;   // fold 2*log2e into Q
    int t = threadIdx.x, w = t >> 6, ln = t & 63;
    const float* ib = in + (size_t)b * DDIM * NN + n0 + ln;
    _Float16* ob = outp + (size_t)b * NN * 32 * 8;      // batch-b fragment space
    int blk = (n0 + ln) >> 4, l15 = ln & 15;
    float ss = 0.f;
#pragma unroll
    for (int h = 0; h < 2; h++) {                  // wave w covers ds in {w, w+4}
        int ds = w + h * 4;
#pragma unroll
        for (int oct = 0; oct < 4; oct++) {
            half8 v;
#pragma unroll
            for (int k = 0; k < 8; k++) {
                float f = ib[(size_t)(ds * 32 + oct * 8 + k) * NN];  // 256B/wave coalesced
                ss = fmaf(f, f, ss);
                v[k] = (_Float16)(f * scale);
            }
            *(half8*)(ob + ((((size_t)blk * 8 + ds) * 4 + oct) * 16 + l15) * 8) = v;
        }
    }
    if (tensor) psum[w][ln] = ss;
    __syncthreads();
    if (tensor && t < 64) {
        float s = psum[0][t] + psum[1][t] + psum[2][t] + psum[3][t];
        int m = n0 + t;
        const float* tp = tgt + (size_t)b * 3 * MM + m;
        // .w carries -log2e*yy (exp2-domain bias); denom handled explicitly in flash
        Vt[(size_t)b * MM + m] = make_float4(tp[0], tp[MM], tp[2 * MM], s * (-LOG2E));
    }
}

// ---------- flash: K-frags direct from L2 (reg ping-pong), no K-loop barriers ----------
__global__ __launch_bounds__(256) void k_flash(const _Float16* __restrict__ Qf,
                                               const _Float16* __restrict__ Kf,
                                               const float4* __restrict__ Vt,
                                               float4* __restrict__ Opart,
                                               float* __restrict__ Mpart) {
    __shared__ floatx4 vtt[MCHUNK];                // 8 KB {v0,v1,v2,-log2e*yy}

    int i = blockIdx.x, t = threadIdx.x;           // grid 512 = xcd(8) x j(64)
    int xcd = i & 7, j = i >> 3;
    int b = xcd >> 1, nhalf = xcd & 1;             // per-XCD K[b] slice (2 MB) L2-resident
    int chunk = j & 7, ntile = nhalf * 8 + (j >> 3);

    int wave = t >> 6, lane = t & 63, quad = lane >> 4, l15 = lane & 15;
    int m0 = chunk * MCHUNK;

    // whole-chunk V(+yy in .w) staged ONCE; the only barrier in this kernel
    {
        const float4* vb = Vt + (size_t)b * MM + m0;
        for (int r = t; r < MCHUNK; r += 256) {
            float4 g = vb[r];
            vtt[r] = (floatx4){g.x, g.y, g.z, g.w};
        }
    }

    // persistent Q fragments: 64 n x 256 d per wave (128 VGPRs), fragment-order loads
    int nblk0 = ntile * 16 + wave * 4;
    const half8* qp = (const half8*)Qf + (size_t)b * NN * 32;
    half8 qf[4][8];
#pragma unroll
    for (int nb = 0; nb < 4; nb++)
#pragma unroll
        for (int ds = 0; ds < 8; ds++)
            qf[nb][ds] = qp[(((size_t)(nblk0 + nb) * 8 + ds) * 4 + quad) * 16 + l15];

    __syncthreads();

    const floatx4 z4 = {0.f, 0.f, 0.f, 0.f};
    floatx4 o[4] = {z4, z4, z4, z4};               // per-quad partial {o0,o1,o2,denom}
    float mr[4];
#pragma unroll
    for (int nb = 0; nb < 4; nb++) mr[nb] = -__builtin_inff();

    // K-fragment stream: 32 blocks of 16 m; 8 x 1 KB coalesced loads per block.
    const char* kfb = (const char*)(Kf + (size_t)b * NN * DDIM) + (size_t)(m0 >> 4) * 8192
                      + lane * 16;
    half8 abuf[2][8];
#pragma unroll
    for (int ds = 0; ds < 8; ds++) abuf[0][ds] = *(const half8*)(kfb + ds * 1024);

#pragma unroll 2
    for (int mb = 0; mb < 32; mb++) {
        // issue loads for block mb+1 (ping-pong regs), compute block mb
        int nxt = mb + 1 < 32 ? mb + 1 : 31;
        const char* gp = kfb + (size_t)nxt * 8192;
#pragma unroll
        for (int ds = 0; ds < 8; ds++) abuf[(mb + 1) & 1][ds] = *(const half8*)(gp + ds * 1024);

        const half8* a = abuf[mb & 1];
        floatx4 acc[4] = {z4, z4, z4, z4};
#pragma unroll
        for (int ds = 0; ds < 8; ds++)
#pragma unroll
            for (int nb = 0; nb < 4; nb++)
                acc[nb] = __builtin_amdgcn_mfma_f32_16x16x32_f16(a[ds], qf[nb][ds], acc[nb], 0, 0, 0);

        // V + yy for this quad's 4 m's (quad-broadcast LDS reads)
        floatx4 vr[4];
#pragma unroll
        for (int r = 0; r < 4; r++) vr[r] = vtt[mb * 16 + quad * 4 + r];
        floatx4 yv = {vr[0][3], vr[1][3], vr[2][3], vr[3][3]};
#pragma unroll
        for (int r = 0; r < 4; r++) vr[r][3] = 1.0f;    // denom slot

        // per-quad online softmax (exp2 domain) + PV
#pragma unroll
        for (int nb = 0; nb < 4; nb++) {
            acc[nb] = acc[nb] + yv;
            float tm = fmaxf(fmaxf(acc[nb][0], acc[nb][1]), fmaxf(acc[nb][2], acc[nb][3]));
            float mn = fmaxf(mr[nb], tm);
            float al = __builtin_amdgcn_exp2f(mr[nb] - mn);
            mr[nb] = mn;
            o[nb] = o[nb] * al;
#pragma unroll
            for (int r = 0; r < 4; r++) {
                float p = __builtin_amdgcn_exp2f(acc[nb][r] - mn);
                o[nb] = o[nb] + p * vr[r];
            }
        }
    }

    // merge the 4 per-quad partial softmaxes (once per kernel)
#pragma unroll
    for (int nb = 0; nb < 4; nb++) {
        float mq = mr[nb];
        float ma = fmaxf(mq, __shfl_xor(mq, 16, 64));
        ma = fmaxf(ma, __shfl_xor(ma, 32, 64));
        float wgt = __builtin_amdgcn_exp2f(mq - ma);
        floatx4 ow = o[nb] * wgt;
#pragma unroll
        for (int c = 0; c < 4; c++) {
            float v = ow[c];
            v += __shfl_xor(v, 16, 64);
            v += __shfl_xor(v, 32, 64);
            ow[c] = v;
        }
        if (quad == 0) {
            int n = (nblk0 + nb) * 16 + l15;
            size_t idx = (size_t)(chunk * NBATCH + b) * NN + n;
            Opart[idx] = make_float4(ow[0], ow[1], ow[2], ow[3]);
            Mpart[idx] = ma;
        }
    }
}

// ---------- combine the 8 m-chunk partials per (b,n) ----------
__global__ __launch_bounds__(128) void k_combine(const float4* __restrict__ Opart,
                                                 const float* __restrict__ Mpart,
                                                 float* __restrict__ out) {
    int idx = blockIdx.x * 128 + threadIdx.x;      // b*NN + n
    int b = idx >> 12, n = idx & (NN - 1);
    float mstar = -__builtin_inff();
#pragma unroll
    for (int j = 0; j < NCHUNK; j++)
        mstar = fmaxf(mstar, Mpart[(size_t)(j * NBATCH + b) * NN + n]);
    float o0 = 0.f, o1 = 0.f, o2 = 0.f, l = 0.f;
#pragma unroll
    for (int j = 0; j < NCHUNK; j++) {
        size_t id = (size_t)(j * NBATCH + b) * NN + n;
        float w = __builtin_amdgcn_exp2f(Mpart[id] - mstar);
        float4 P = Opart[id];
        o0 = fmaf(w, P.x, o0); o1 = fmaf(w, P.y, o1);
        o2 = fmaf(w, P.z, o2); l  = fmaf(w, P.w, l);
    }
    out[(size_t)(b * 3 + 0) * NN + n] = o0 / l;
    out[(size_t)(b * 3 + 1) * NN + n] = o1 / l;
    out[(size_t)(b * 3 + 2) * NN + n] = o2 / l;
}

extern "C" void kernel_launch(void* const* d_in, const int* in_sizes, int n_in,
                              void* d_out, int out_size, void* d_ws, size_t ws_size,
                              hipStream_t stream) {
    const float* tgt     = (const float*)d_in[1];
    const float* src_emb = (const float*)d_in[2];
    const float* tgt_emb = (const float*)d_in[3];
    float* out = (float*)d_out;

    char* ws = (char*)d_ws;
    // ws: Qf 8.39M | Kf 8.39M | Vt 256K | Opart 2M | Mpart 512K  (~19.5 MB)
    _Float16* Qf  = (_Float16*)(ws);
    _Float16* Kf  = (_Float16*)(ws + 8388608);
    float4*   Vt  = (float4*)  (ws + 16777216);
    float4*   Op  = (float4*)  (ws + 17039360);
    float*    Mp  = (float*)   (ws + 19136512);

    hipLaunchKernelGGL(k_prep,    dim3(512), dim3(256), 0, stream,
                       src_emb, tgt_emb, tgt, Qf, Kf, Vt);
    hipLaunchKernelGGL(k_flash,   dim3(512), dim3(256), 0, stream, Qf, Kf, Vt, Op, Mp);
    hipLaunchKernelGGL(k_combine, dim3(128), dim3(128), 0, stream, Op, Mp, out);
}